// Round 8
// baseline (887.983 us; speedup 1.0000x reference)
//
#include <hip/hip_runtime.h>

// SelfAttention: B=1, S_img=3072, S_txt=256, D=1920, H=30, hd=64. All I/O fp32.
// Score path (Q/K proj + QK^T) in split precision (bf16x2 GEMM, fp16 hi/lo q,k);
// value path (V, P, out-proj) in fp16 MFMA with fp32 accumulate.
constexpr int S_TOT  = 3328;
constexpr int S_TXT  = 256;
constexpr int DMODEL = 1920;
constexpr int NHEAD  = 30;
constexpr int HD     = 64;

typedef _Float16 half8 __attribute__((ext_vector_type(8)));
typedef _Float16 half4v __attribute__((ext_vector_type(4)));
typedef float    f32x4 __attribute__((ext_vector_type(4)));
typedef short    bh8   __attribute__((ext_vector_type(8)));   // 8 bf16 in shorts

__device__ __forceinline__ f32x4 mfma16h(half8 a, half8 b, f32x4 c) {
    return __builtin_amdgcn_mfma_f32_16x16x32_f16(a, b, c, 0, 0, 0);
}
__device__ __forceinline__ f32x4 mfma16b(bh8 a, bh8 b, f32x4 c) {
    return __builtin_amdgcn_mfma_f32_16x16x32_bf16(a, b, c, 0, 0, 0);
}
// async global->LDS, 16B per lane; lds dst = wave-uniform base + lane*16
__device__ __forceinline__ void gload16(void* lds, const void* g) {
    __builtin_amdgcn_global_load_lds(
        (const __attribute__((address_space(1))) void*)g,
        (__attribute__((address_space(3))) void*)lds, 16, 0, 0);
}

__device__ __forceinline__ unsigned f2u(float x){ union{float f;unsigned u;}c; c.f=x; return c.u; }
__device__ __forceinline__ float u2f(unsigned x){ union{unsigned u;float f;}c; c.u=x; return c.f; }

// max with DPP-shifted self (VALU-only cross-lane; no DS pipe, no ds_swizzle).
#define MAXDPP(v, ctrl)                                                        \
    v = fmaxf(v, u2f(__builtin_amdgcn_update_dpp(                              \
            (int)f2u(v), (int)f2u(v), (ctrl), 0xf, 0xf, false)))

// split 8 consecutive LDS f32 into bf16 hi (truncate) + bf16 lo (residual, RTZ).
__device__ __forceinline__ void split8(const float* p, bh8& hi, bh8& lo) {
    float4 f0 = *(const float4*)p;
    float4 f1 = *(const float4*)(p + 4);
    float f[8] = {f0.x, f0.y, f0.z, f0.w, f1.x, f1.y, f1.z, f1.w};
    union { bh8 v; unsigned short u[8]; } H, L;
    #pragma unroll
    for (int e = 0; e < 8; ++e) {
        unsigned ub = f2u(f[e]);
        H.u[e] = (unsigned short)(ub >> 16);
        float r = f[e] - u2f(ub & 0xFFFF0000u);      // exact residual
        L.u[e] = (unsigned short)(f2u(r) >> 16);
    }
    hi = H.v; lo = L.v;
}

// ---------------------------------------------------------------------------
// fp32 -> fp16 converts: seg 0=enc,1=hid -> xh; seg 2 = Wv -> Wvh (in d_out).
// ---------------------------------------------------------------------------
__global__ __launch_bounds__(256) void cvt_xwv(
    const float* __restrict__ hid, const float* __restrict__ enc,
    const float* __restrict__ Wv,
    _Float16* __restrict__ xh, _Float16* __restrict__ Wvh)
{
    const int seg = blockIdx.y;
    const float* src; _Float16* dst; int n;
    switch (seg) {
        case 0:  src = enc; dst = xh;                  n = S_TXT * DMODEL;  break;
        case 1:  src = hid; dst = xh + S_TXT * DMODEL; n = 3072 * DMODEL;   break;
        default: src = Wv;  dst = Wvh;                 n = DMODEL * DMODEL; break;
    }
    for (int i = (blockIdx.x * 256 + threadIdx.x) * 4; i < n; i += gridDim.x * 256 * 4) {
        float4 v = *(const float4*)(src + i);
        half4v h = {(_Float16)v.x, (_Float16)v.y, (_Float16)v.z, (_Float16)v.w};
        *(half4v*)(dst + i) = h;
    }
}

__global__ __launch_bounds__(256) void cvt_wo(const float* __restrict__ Wo,
                                              _Float16* __restrict__ Woh)
{
    const int n = DMODEL * DMODEL;
    for (int i = (blockIdx.x * 256 + threadIdx.x) * 4; i < n; i += gridDim.x * 256 * 4) {
        float4 v = *(const float4*)(Wo + i);
        half4v h = {(_Float16)v.x, (_Float16)v.y, (_Float16)v.z, (_Float16)v.w};
        *(half4v*)(Woh + i) = h;
    }
}

// ---------------------------------------------------------------------------
// V projection (m97 structure, fp16): 128x128 tile, BK=32, global_load_lds.
// Epilogue: +bv, transpose to v_hT [head][d][s] via wave-local LDS.
// ---------------------------------------------------------------------------
__global__ __launch_bounds__(256) void gemm_v(
    const _Float16* __restrict__ xh,    // [3328][1920]
    const _Float16* __restrict__ Wvh,   // [1920][1920]
    const float* __restrict__ bv,
    _Float16* __restrict__ v_hT)
{
    extern __shared__ __attribute__((aligned(16))) char smem[];
    _Float16* As = (_Float16*)smem;             // 128*32
    _Float16* Bs = (_Float16*)(smem + 8192);    // 128*32

    const int tid  = threadIdx.x;
    const int wave = tid >> 6;
    const int lane = tid & 63;
    const int l16  = lane & 15;
    const int quad = lane >> 4;

    const int m0 = blockIdx.x * 128;
    const int n0 = blockIdx.y * 128;
    const int wm = (wave >> 1) * 64;
    const int wn = (wave & 1) * 64;

    const _Float16* gA = xh  + (size_t)(m0 + wave * 32 + (lane >> 2)) * DMODEL + ((lane & 3) << 3);
    const _Float16* gB = Wvh + (size_t)(n0 + wave * 32 + (lane >> 2)) * DMODEL + ((lane & 3) << 3);
    _Float16* lA = As + wave * 32 * 32;
    _Float16* lB = Bs + wave * 32 * 32;

    f32x4 acc[4][4];
    #pragma unroll
    for (int j = 0; j < 4; ++j)
        #pragma unroll
        for (int i = 0; i < 4; ++i) acc[j][i] = (f32x4){0.f, 0.f, 0.f, 0.f};

    for (int k0 = 0; k0 < DMODEL; k0 += 32) {
        __syncthreads();
        gload16(lA,        gA + k0);
        gload16(lA + 512,  gA + 16 * DMODEL + k0);
        gload16(lB,        gB + k0);
        gload16(lB + 512,  gB + 16 * DMODEL + k0);
        __syncthreads();
        half8 af[4], bf[4];
        #pragma unroll
        for (int j = 0; j < 4; ++j)
            af[j] = *(const half8*)(As + (wm + j * 16 + l16) * 32 + quad * 8);
        #pragma unroll
        for (int i = 0; i < 4; ++i)
            bf[i] = *(const half8*)(Bs + (wn + i * 16 + l16) * 32 + quad * 8);
        #pragma unroll
        for (int j = 0; j < 4; ++j)
            #pragma unroll
            for (int i = 0; i < 4; ++i)
                acc[j][i] = mfma16h(af[j], bf[i], acc[j][i]);
    }
    __syncthreads();   // staging LDS dead; vt reuses it

    const int h = (n0 + wn) / 64;
    _Float16* vt = (_Float16*)smem + wave * 64 * 72;   // [64 d][72 pad]
    #pragma unroll
    for (int j = 0; j < 4; ++j)
        #pragma unroll
        for (int r = 0; r < 4; ++r)
            #pragma unroll
            for (int i = 0; i < 4; ++i)
                vt[(i * 16 + l16) * 72 + j * 16 + quad * 4 + r] =
                    (_Float16)(acc[j][i][r] + bv[n0 + wn + i * 16 + l16]);
    __asm__ volatile("" ::: "memory");   // order LDS writes before reads (same wave)
    const int dl = lane >> 3;
    const int sl = (lane & 7) << 3;
    #pragma unroll
    for (int t = 0; t < 8; ++t) {
        const int d = t * 8 + dl;
        half8 vv = *(const half8*)(vt + d * 72 + sl);
        *(half8*)(v_hT + (size_t)(h * HD + d) * S_TOT + m0 + wm + sl) = vv;
    }
}

// ---------------------------------------------------------------------------
// Q/K projection in split precision (bf16x2, 3 MFMAs) -> ~fp32-exact.
// Epilogue: LN(+rope, q*0.125*log2e), dual store fp16 hi + fp16 lo*2^10.
// ---------------------------------------------------------------------------
__global__ __launch_bounds__(256) void gemm_qk(
    const float* __restrict__ hid, const float* __restrict__ enc,
    const float* __restrict__ Wq, const float* __restrict__ Wk,
    const float* __restrict__ bq, const float* __restrict__ bk,
    const float* __restrict__ rcos, const float* __restrict__ rsin,
    _Float16* __restrict__ q_h, _Float16* __restrict__ k_h,
    _Float16* __restrict__ q_lo, _Float16* __restrict__ k_lo)
{
    extern __shared__ __attribute__((aligned(16))) char smem[];
    float* As = (float*)smem;             // [128][32] f32
    float* Bs = (float*)(smem + 16384);   // [128][32] f32

    const int tid  = threadIdx.x;
    const int wave = tid >> 6;
    const int lane = tid & 63;
    const int l16  = lane & 15;
    const int quad = lane >> 4;

    const int m0  = blockIdx.x * 128;
    const int n0g = blockIdx.y * 128;
    const int zz  = (n0g >= DMODEL);       // 0=q 1=k (block-uniform; 128|1920)
    const int nloc = n0g - zz * DMODEL;
    const int wm = (wave >> 1) * 64;
    const int wn = (wave & 1) * 64;

    const float* aSrc = (m0 < S_TXT) ? (enc + (size_t)m0 * DMODEL)
                                     : (hid + (size_t)(m0 - S_TXT) * DMODEL);
    const float* bSrc = (zz ? Wk : Wq) + (size_t)nloc * DMODEL;

    const float* gA = aSrc + (size_t)(wave * 32 + (lane >> 3)) * DMODEL + ((lane & 7) << 2);
    const float* gB = bSrc + (size_t)(wave * 32 + (lane >> 3)) * DMODEL + ((lane & 7) << 2);
    float* lA = As + wave * 32 * 32;
    float* lB = Bs + wave * 32 * 32;

    f32x4 acc[4][4];
    #pragma unroll
    for (int j = 0; j < 4; ++j)
        #pragma unroll
        for (int i = 0; i < 4; ++i) acc[j][i] = (f32x4){0.f, 0.f, 0.f, 0.f};

    for (int k0 = 0; k0 < DMODEL; k0 += 32) {
        __syncthreads();
        #pragma unroll
        for (int t = 0; t < 4; ++t) {
            gload16(lA + t * 256, gA + (size_t)(t * 8) * DMODEL + k0);
            gload16(lB + t * 256, gB + (size_t)(t * 8) * DMODEL + k0);
        }
        __syncthreads();
        bh8 ah[4], al[4], bhv[4], blv[4];
        #pragma unroll
        for (int j = 0; j < 4; ++j)
            split8(As + (wm + j * 16 + l16) * 32 + quad * 8, ah[j], al[j]);
        #pragma unroll
        for (int i = 0; i < 4; ++i)
            split8(Bs + (wn + i * 16 + l16) * 32 + quad * 8, bhv[i], blv[i]);
        #pragma unroll
        for (int j = 0; j < 4; ++j)
            #pragma unroll
            for (int i = 0; i < 4; ++i) {
                acc[j][i] = mfma16b(ah[j], bhv[i], acc[j][i]);
                acc[j][i] = mfma16b(al[j], bhv[i], acc[j][i]);
                acc[j][i] = mfma16b(ah[j], blv[i], acc[j][i]);
            }
    }

    const int h = (nloc + wn) / 64;        // head for this wave's 64 cols
    const float* bias = zz ? bk : bq;
    _Float16* dhi = zz ? k_h : q_h;
    _Float16* dlo = zz ? k_lo : q_lo;
    // fold 1/sqrt(64) * log2(e) into q: attn computes softmax via exp2
    const float qscale = zz ? 1.f : 0.18033688011112042f;
    const bool rope = (m0 >= S_TXT);          // block-uniform (128|256)

    #pragma unroll
    for (int j = 0; j < 4; ++j) {
        #pragma unroll
        for (int r = 0; r < 4; ++r) {
            const int s = m0 + wm + j * 16 + quad * 4 + r;
            float x[4], s1 = 0.f, s2 = 0.f;
            #pragma unroll
            for (int i = 0; i < 4; ++i) {
                x[i] = acc[j][i][r] + bias[nloc + wn + i * 16 + l16];
                s1 += x[i];
                s2 += x[i] * x[i];
            }
            #pragma unroll
            for (int off = 1; off <= 8; off <<= 1) {
                s1 += __shfl_xor(s1, off);
                s2 += __shfl_xor(s2, off);
            }
            const float mu   = s1 * (1.f / 64.f);
            const float var  = fmaxf(s2 * (1.f / 64.f) - mu * mu, 0.f);
            const float rstd = rsqrtf(var + 1e-5f);
            float xn[4];
            #pragma unroll
            for (int i = 0; i < 4; ++i) xn[i] = (x[i] - mu) * rstd;
            float o[4];
            if (rope) {
                const int pos = s - S_TXT;
                #pragma unroll
                for (int i = 0; i < 4; ++i) {
                    const int d = i * 16 + l16;
                    const float c  = rcos[(size_t)pos * HD + d];
                    const float si = rsin[(size_t)pos * HD + d];
                    const float rot = (i < 2) ? -xn[i ^ 2] : xn[i ^ 2];
                    o[i] = xn[i] * c + rot * si;
                }
            } else {
                #pragma unroll
                for (int i = 0; i < 4; ++i) o[i] = xn[i];
            }
            #pragma unroll
            for (int i = 0; i < 4; ++i) {
                const float vv = o[i] * qscale;
                const _Float16 hv = (_Float16)vv;
                const size_t idx = (size_t)(h * S_TOT + s) * HD + i * 16 + l16;
                dhi[idx] = hv;
                // residual scaled 2^10 to avoid fp16 denormals; attn folds 2^-10
                dlo[idx] = (_Float16)((vv - (float)hv) * 1024.f);
            }
        }
    }
}

// ---------------------------------------------------------------------------
// Flash attention, online softmax in exp2 units. s = qh*kh + 2^-10*(ql*kh+qh*kl).
// 32 q-rows per wave (block = 128 rows); K/Kl/V/Pl XOR-swizzled; conflicts = 0.
// T13 defer-max: skip the DPP max-reduce + l/o rescale unless any lane's local
// max exceeds m + 11 (log2 units; P <= 2^11 = 2048, fp16-safe; l,o in f32).
// Pipeline: Khi double-buffered (staged 1 ahead); Ksl single-buffered (staged
// after b2 — Ksl reads are data-dep-complete before b2); V single-buffered
// (staged after b3 with lgkmcnt(0) guard: raw s_barrier is neither a DS-drain
// nor a compiler fence — the clobbered asm provides both).
// LDS: Khi[2][64][64] | Ksl[64][64] | Vs[64][64] | Pl[4][16][64] = 40960 B.
// ---------------------------------------------------------------------------
__global__ __launch_bounds__(256, 3) void attn(
    const _Float16* __restrict__ q_h,  const _Float16* __restrict__ q_lo,
    const _Float16* __restrict__ k_h,  const _Float16* __restrict__ k_lo,
    const _Float16* __restrict__ v_hT,
    _Float16* __restrict__ aout)
{
    extern __shared__ __attribute__((aligned(16))) char smem[];
    _Float16* KsB  = (_Float16*)smem;              // [2][64 kv][64 d] hi (swizzled)
    _Float16* Ksl  = (_Float16*)(smem + 16384);    // [64 kv][64 d] lo (swizzled)
    _Float16* Vs   = (_Float16*)(smem + 24576);    // [64 d][64 kv] (swizzled)
    _Float16* Pl   = (_Float16*)(smem + 32768);    // [4][16][64] (swizzled)

    const int tid  = threadIdx.x;
    const int wave = tid >> 6;
    const int lane = tid & 63;
    const int l16  = lane & 15;
    const int quad = lane >> 4;
    const int h  = blockIdx.y;
    const int q0 = blockIdx.x * 128 + wave * 32;

    // q fragments for 32 rows (j=0: rows 0..15, j=1: rows 16..31)
    const _Float16* qbase  = q_h  + (size_t)(h * S_TOT + q0) * HD;
    const _Float16* qlbase = q_lo + (size_t)(h * S_TOT + q0) * HD;
    half8 aq0[2], aq1[2], aql0[2], aql1[2];
    #pragma unroll
    for (int j = 0; j < 2; ++j) {
        aq0[j]  = *(const half8*)(qbase  + (j * 16 + l16) * HD + quad * 8);
        aq1[j]  = *(const half8*)(qbase  + (j * 16 + l16) * HD + 32 + quad * 8);
        aql0[j] = *(const half8*)(qlbase + (j * 16 + l16) * HD + quad * 8);
        aql1[j] = *(const half8*)(qlbase + (j * 16 + l16) * HD + 32 + quad * 8);
    }

    const _Float16* kbase  = k_h  + (size_t)h * S_TOT * HD;
    const _Float16* klbase = k_lo + (size_t)h * S_TOT * HD;
    const _Float16* vbase  = v_hT + (size_t)h * HD * S_TOT;

    // staging: per wave 16 rows each of K, Kl, V (2 gloads each).
    // Global source chunk pre-swizzled: chunk' = (lane&7) ^ (row&7); LDS dest
    // stays linear (global_load_lds constraint), reads XOR with row&7.
    const int srow = lane >> 3;                    // row within 8-row group
    const int schk = ((lane & 7) ^ srow) << 3;     // swizzled chunk, in halves
    const _Float16* gK  = kbase  + (size_t)(wave * 16 + srow) * HD + schk;
    const _Float16* gKl = klbase + (size_t)(wave * 16 + srow) * HD + schk;
    const _Float16* gV  = vbase  + (size_t)(wave * 16 + srow) * S_TOT + schk;

    // read-side swizzle: chunk quad lives at physical (quad ^ (row&7));
    // row&7 == l16&7 for rows i*16+l16 -> per-thread constant offsets.
    const int c0 = (quad ^ (l16 & 7)) << 3;        // halves
    const int c1 = c0 ^ 32;                        // chunk ^ 4

    f32x4 o[2][4];
    float m_i[2][4], l_i[2][4];
    #pragma unroll
    for (int j = 0; j < 2; ++j)
        #pragma unroll
        for (int i = 0; i < 4; ++i) {
            o[j][i] = (f32x4){0.f, 0.f, 0.f, 0.f};
            m_i[j][i] = -1e30f; l_i[j][i] = 0.f;
        }

    constexpr int NT = S_TOT / 64;   // 52

    // stage K hi of tile (kv0/64) into parity p: 2 gloads/wave
    auto stageKhi = [&](int kv0, int p) {
        _Float16* lK = KsB + p * 4096 + wave * 1024;
        gload16(lK,       gK + (size_t)kv0 * HD);
        gload16(lK + 512, gK + (size_t)(kv0 + 8) * HD);
    };
    // stage K lo into the single Ksl buffer: 2 gloads/wave
    auto stageKsl = [&](int kv0) {
        _Float16* lKl = Ksl + wave * 1024;
        gload16(lKl,       gKl + (size_t)kv0 * HD);
        gload16(lKl + 512, gKl + (size_t)(kv0 + 8) * HD);
    };
    // stage V into the single V buffer: 2 gloads/wave
    auto stageV = [&](int kv0) {
        _Float16* lV = Vs + wave * 1024;
        gload16(lV,       gV + kv0);
        gload16(lV + 512, gV + kv0 + 8 * S_TOT);
    };

    stageKhi(0, 0);                                // prologue
    stageKsl(0);
    stageV(0);
    for (int t = 0; t < NT; ++t) {
        const int cur = t & 1;
        const bool isLast = (t == NT - 1);
        if (!isLast) {
            stageKhi((t + 1) * 64, cur ^ 1);       // issue next tile's K hi
            // outstanding: [Khi(t)2, Ksl(t)2, V(t)2, Khi(t+1)2] -> drain first 4
            asm volatile("s_waitcnt vmcnt(4)" ::: "memory");
        } else {
            asm volatile("s_waitcnt vmcnt(2)" ::: "memory");   // leave V(t)
        }
        __builtin_amdgcn_s_barrier();              // b1: K hi+lo of t visible
        const _Float16* Ks = KsB + cur * 4096;

        // ---- scores (q pre-scaled by log2e/8; lo terms folded with 2^-10) ----
        f32x4 sc[2][4];
        #pragma unroll
        for (int i = 0; i < 4; ++i) {
            const int rb = (i * 16 + l16) * 64;
            half8 b0 = *(const half8*)(Ks  + rb + c0);
            half8 b1 = *(const half8*)(Ks  + rb + c1);
            half8 d0 = *(const half8*)(Ksl + rb + c0);
            half8 d1 = *(const half8*)(Ksl + rb + c1);
            #pragma unroll
            for (int j = 0; j < 2; ++j) {
                f32x4 s  = (f32x4){0.f, 0.f, 0.f, 0.f};
                f32x4 s2 = (f32x4){0.f, 0.f, 0.f, 0.f};
                s  = mfma16h(aq0[j],  b0, s);   s  = mfma16h(aq1[j],  b1, s);
                s2 = mfma16h(aql0[j], b0, s2);  s2 = mfma16h(aql1[j], b1, s2);
                s2 = mfma16h(aq0[j],  d0, s2);  s2 = mfma16h(aq1[j],  d1, s2);
                sc[j][i] = s + s2 * 0.0009765625f;
            }
        }
        // ---- online softmax (defer-max): rows (j, quad*4+r) ----
        half8 ap0[2], ap1[2];
        #pragma unroll
        for (int j = 0; j < 2; ++j) {
            #pragma unroll
            for (int r = 0; r < 4; ++r) {
                const float mxl = fmaxf(fmaxf(sc[j][0][r], sc[j][1][r]),
                                        fmaxf(sc[j][2][r], sc[j][3][r]));
                if (__any(mxl > m_i[j][r] + 11.f)) {   // rare after warmup
                    float mx = mxl;
                    MAXDPP(mx, 0xB1);    // quad_perm xor1
                    MAXDPP(mx, 0x4E);    // quad_perm xor2
                    MAXDPP(mx, 0x124);   // row_ror:4
                    MAXDPP(mx, 0x128);   // row_ror:8 -> row max (16-lane group)
                    const float mnew  = fmaxf(m_i[j][r], mx);
                    const float alpha = __builtin_amdgcn_exp2f(m_i[j][r] - mnew);
                    m_i[j][r] = mnew;
                    l_i[j][r] *= alpha;
                    #pragma unroll
                    for (int i = 0; i < 4; ++i) o[j][i][r] *= alpha;
                }
                const float mref = m_i[j][r];
                const int ro  = quad * 4 + r;
                const int rsw = ((quad & 1) * 4 + r) << 3;   // (ro&7)<<3
                float rs = 0.f;
                #pragma unroll
                for (int i = 0; i < 4; ++i) {
                    float p = __builtin_amdgcn_exp2f(sc[j][i][r] - mref);
                    rs += p;
                    Pl[wave * 1024 + ro * 64 + ((i * 16 + l16) ^ rsw)] = (_Float16)p;
                }
                l_i[j][r] += rs;   // per-lane partial
            }
            __asm__ volatile("" ::: "memory");   // order P writes before reads
            // reads: row l16, chunks (quad^(l16&7)) and ^4 -> same c0/c1 geometry
            ap0[j] = *(const half8*)(Pl + wave * 1024 + l16 * 64 + c0);
            ap1[j] = *(const half8*)(Pl + wave * 1024 + l16 * 64 + c1);
            __asm__ volatile("" ::: "memory");   // reads before j=1 overwrites
        }
        // V(t) arrival: outstanding = [V(t)2, Khi(t+1)2] -> drain V(t)
        if (!isLast) asm volatile("s_waitcnt vmcnt(2)" ::: "memory");
        else         asm volatile("s_waitcnt vmcnt(0)" ::: "memory");
        __builtin_amdgcn_s_barrier();              // b2: all V(t) visible
        // Ksl buffer free: every wave's Ksl reads were consumed by the QK
        // MFMAs -> sc -> softmax, all before b2 (data dependency).
        if (!isLast) stageKsl((t + 1) * 64);
        // ---- PV ----
        #pragma unroll
        for (int i = 0; i < 4; ++i) {
            const int rb = (i * 16 + l16) * 64;
            half8 vb0 = *(const half8*)(Vs + rb + c0);
            half8 vb1 = *(const half8*)(Vs + rb + c1);
            #pragma unroll
            for (int j = 0; j < 2; ++j) {
                o[j][i] = mfma16h(ap0[j], vb0, o[j][i]);
                o[j][i] = mfma16h(ap1[j], vb1, o[j][i]);
            }
        }
        if (!isLast) {
            // drain this wave's DS reads (V) before signaling b3; the clobber
            // also fences compiler LDS-op motion across the raw barrier.
            asm volatile("s_waitcnt lgkmcnt(0)" ::: "memory");
            __builtin_amdgcn_s_barrier();          // b3: V buffer free
            stageV((t + 1) * 64);                  // hides under next QK+sm
        }
    }
    // ---- final: reduce deferred l partials, normalize, store ----
    #pragma unroll
    for (int j = 0; j < 2; ++j)
        #pragma unroll
        for (int r = 0; r < 4; ++r) {
            float l = l_i[j][r];
            l += __shfl_xor(l, 1);
            l += __shfl_xor(l, 2);
            l += __shfl_xor(l, 4);
            l += __shfl_xor(l, 8);
            const float inv = 1.f / l;
            const int srow2 = q0 + j * 16 + quad * 4 + r;
            #pragma unroll
            for (int i = 0; i < 4; ++i)
                aout[(size_t)srow2 * DMODEL + h * HD + i * 16 + l16] =
                    (_Float16)(o[j][i][r] * inv);
        }
}

// ---------------------------------------------------------------------------
// Out projection (m97 structure) + bias + row remap, fp32 out.
// ---------------------------------------------------------------------------
__global__ __launch_bounds__(256) void gemm_out(
    const _Float16* __restrict__ A,    // [3328][1920] f16
    const _Float16* __restrict__ Woh,  // [1920][1920] f16
    const float* __restrict__ bo,
    float* __restrict__ out)
{
    extern __shared__ __attribute__((aligned(16))) char smem[];
    _Float16* As = (_Float16*)smem;
    _Float16* Bs = (_Float16*)(smem + 8192);

    const int tid  = threadIdx.x;
    const int wave = tid >> 6;
    const int lane = tid & 63;
    const int l16  = lane & 15;
    const int quad = lane >> 4;

    const int m0 = blockIdx.x * 128;
    const int n0 = blockIdx.y * 128;
    const int wm = (wave >> 1) * 64;
    const int wn = (wave & 1) * 64;

    const _Float16* gA = A   + (size_t)(m0 + wave * 32 + (lane >> 2)) * DMODEL + ((lane & 3) << 3);
    const _Float16* gB = Woh + (size_t)(n0 + wave * 32 + (lane >> 2)) * DMODEL + ((lane & 3) << 3);
    _Float16* lA = As + wave * 32 * 32;
    _Float16* lB = Bs + wave * 32 * 32;

    f32x4 acc[4][4];
    #pragma unroll
    for (int j = 0; j < 4; ++j)
        #pragma unroll
        for (int i = 0; i < 4; ++i) acc[j][i] = (f32x4){0.f, 0.f, 0.f, 0.f};

    for (int k0 = 0; k0 < DMODEL; k0 += 32) {
        __syncthreads();
        gload16(lA,        gA + k0);
        gload16(lA + 512,  gA + 16 * DMODEL + k0);
        gload16(lB,        gB + k0);
        gload16(lB + 512,  gB + 16 * DMODEL + k0);
        __syncthreads();
        half8 af[4], bf[4];
        #pragma unroll
        for (int j = 0; j < 4; ++j)
            af[j] = *(const half8*)(As + (wm + j * 16 + l16) * 32 + quad * 8);
        #pragma unroll
        for (int i = 0; i < 4; ++i)
            bf[i] = *(const half8*)(Bs + (wn + i * 16 + l16) * 32 + quad * 8);
        #pragma unroll
        for (int j = 0; j < 4; ++j)
            #pragma unroll
            for (int i = 0; i < 4; ++i)
                acc[j][i] = mfma16h(af[j], bf[i], acc[j][i]);
    }
    #pragma unroll
    for (int j = 0; j < 4; ++j) {
        #pragma unroll
        for (int i = 0; i < 4; ++i) {
            const int n = n0 + wn + i * 16 + l16;
            const float bb = bo[n];
            #pragma unroll
            for (int r = 0; r < 4; ++r) {
                const int m = m0 + wm + j * 16 + quad * 4 + r;
                const int orow = (m >= S_TXT) ? (m - S_TXT) : (m + 3072);
                out[(size_t)orow * DMODEL + n] = acc[j][i][r] + bb;
            }
        }
    }
}

// ---------------------------------------------------------------------------
extern "C" void kernel_launch(void* const* d_in, const int* in_sizes, int n_in,
                              void* d_out, int out_size, void* d_ws, size_t ws_size,
                              hipStream_t stream) {
    const float* hid  = (const float*)d_in[0];
    const float* enc  = (const float*)d_in[1];
    const float* rcos = (const float*)d_in[2];
    const float* rsin = (const float*)d_in[3];
    const float* Wq   = (const float*)d_in[4];
    const float* bq   = (const float*)d_in[5];
    const float* Wk   = (const float*)d_in[6];
    const float* bk   = (const float*)d_in[7];
    const float* Wv   = (const float*)d_in[8];
    const float* bv   = (const float*)d_in[9];
    const float* Wo   = (const float*)d_in[10];
    const float* bo   = (const float*)d_in[11];

    // ws layout (51.1 MB, unchanged):
    //   A [0, 12.78M)        xh, later aout
    //   B [12.78M, 25.56M)   q_h, later Woh
    //   C [25.56M, 38.34M)   k_h
    //   D [38.34M, 51.12M)   v_hT
    // d_out (25.56 MB fp32) time-shared:
    //   phase 1 (cvt_xwv..gemm_v):   Wvh fp16 at [0, 7.37M)
    //   phase 2 (gemm_qk..attn):     q_lo at [0,12.78M), k_lo at [12.78M,25.56M)
    //   phase 3 (gemm_out):          final fp32 output
    char* ws = (char*)d_ws;
    _Float16* xh   = (_Float16*)(ws + 0);
    _Float16* aout = (_Float16*)(ws + 0);
    _Float16* q_h  = (_Float16*)(ws + 12779520);
    _Float16* Woh  = (_Float16*)(ws + 12779520);
    _Float16* k_h  = (_Float16*)(ws + 25559040);
    _Float16* v_hT = (_Float16*)(ws + 38338560);
    _Float16* Wvh  = (_Float16*)d_out;
    _Float16* q_lo = (_Float16*)d_out;
    _Float16* k_lo = (_Float16*)((char*)d_out + 12779520);

    cvt_xwv<<<dim3(128, 3), 256, 0, stream>>>(hid, enc, Wv, xh, Wvh);
    gemm_v<<<dim3(26, 15), 256, 36864, stream>>>(xh, Wvh, bv, v_hT);
    gemm_qk<<<dim3(26, 30), 256, 32768, stream>>>(
        hid, enc, Wq, Wk, bq, bk, rcos, rsin, q_h, k_h, q_lo, k_lo);
    attn<<<dim3(26, NHEAD), 256, 40960, stream>>>(q_h, q_lo, k_h, k_lo, v_hT, aout);
    cvt_wo<<<dim3(128), 256, 0, stream>>>(Wo, Woh);
    gemm_out<<<dim3(26, 15), 256, 16384, stream>>>(aout, Woh, bo, (float*)d_out);
}

// Round 10
// 773.383 us; speedup vs baseline: 1.1482x; 1.1482x over previous
//
#include <hip/hip_runtime.h>

// SelfAttention: B=1, S_img=3072, S_txt=256, D=1920, H=30, hd=64. All I/O fp32.
// Score path (Q/K proj + QK^T) in split precision (bf16x2 GEMM, fp16 hi/lo q,k);
// value path (V, P, out-proj) in fp16 MFMA with fp32 accumulate.
constexpr int S_TOT  = 3328;
constexpr int S_TXT  = 256;
constexpr int DMODEL = 1920;
constexpr int NHEAD  = 30;
constexpr int HD     = 64;

typedef _Float16 half8 __attribute__((ext_vector_type(8)));
typedef _Float16 half4v __attribute__((ext_vector_type(4)));
typedef float    f32x4 __attribute__((ext_vector_type(4)));
typedef short    bh8   __attribute__((ext_vector_type(8)));   // 8 bf16 in shorts

__device__ __forceinline__ f32x4 mfma16h(half8 a, half8 b, f32x4 c) {
    return __builtin_amdgcn_mfma_f32_16x16x32_f16(a, b, c, 0, 0, 0);
}
__device__ __forceinline__ f32x4 mfma16b(bh8 a, bh8 b, f32x4 c) {
    return __builtin_amdgcn_mfma_f32_16x16x32_bf16(a, b, c, 0, 0, 0);
}
// async global->LDS, 16B per lane; lds dst = wave-uniform base + lane*16
__device__ __forceinline__ void gload16(void* lds, const void* g) {
    __builtin_amdgcn_global_load_lds(
        (const __attribute__((address_space(1))) void*)g,
        (__attribute__((address_space(3))) void*)lds, 16, 0, 0);
}

__device__ __forceinline__ unsigned f2u(float x){ union{float f;unsigned u;}c; c.f=x; return c.u; }
__device__ __forceinline__ float u2f(unsigned x){ union{unsigned u;float f;}c; c.u=x; return c.f; }

// max with DPP-shifted self (VALU-only cross-lane; no DS pipe, no ds_swizzle).
#define MAXDPP(v, ctrl)                                                        \
    v = fmaxf(v, u2f(__builtin_amdgcn_update_dpp(                              \
            (int)f2u(v), (int)f2u(v), (ctrl), 0xf, 0xf, false)))

// split 4+4 LDS f32 (two separately-addressed float4s, for swizzled chunks)
// into bf16 hi (truncate) + bf16 lo (residual, RTZ).
__device__ __forceinline__ void split8(const float* p0, const float* p1,
                                       bh8& hi, bh8& lo) {
    float4 f0 = *(const float4*)p0;
    float4 f1 = *(const float4*)p1;
    float f[8] = {f0.x, f0.y, f0.z, f0.w, f1.x, f1.y, f1.z, f1.w};
    union { bh8 v; unsigned short u[8]; } H, L;
    #pragma unroll
    for (int e = 0; e < 8; ++e) {
        unsigned ub = f2u(f[e]);
        H.u[e] = (unsigned short)(ub >> 16);
        float r = f[e] - u2f(ub & 0xFFFF0000u);      // exact residual
        L.u[e] = (unsigned short)(f2u(r) >> 16);
    }
    hi = H.v; lo = L.v;
}

// ---------------------------------------------------------------------------
// fp32 -> fp16 converts: seg 0=enc,1=hid -> xh; seg 2 = Wv -> Wvh (in d_out).
// ---------------------------------------------------------------------------
__global__ __launch_bounds__(256) void cvt_xwv(
    const float* __restrict__ hid, const float* __restrict__ enc,
    const float* __restrict__ Wv,
    _Float16* __restrict__ xh, _Float16* __restrict__ Wvh)
{
    const int seg = blockIdx.y;
    const float* src; _Float16* dst; int n;
    switch (seg) {
        case 0:  src = enc; dst = xh;                  n = S_TXT * DMODEL;  break;
        case 1:  src = hid; dst = xh + S_TXT * DMODEL; n = 3072 * DMODEL;   break;
        default: src = Wv;  dst = Wvh;                 n = DMODEL * DMODEL; break;
    }
    for (int i = (blockIdx.x * 256 + threadIdx.x) * 4; i < n; i += gridDim.x * 256 * 4) {
        float4 v = *(const float4*)(src + i);
        half4v h = {(_Float16)v.x, (_Float16)v.y, (_Float16)v.z, (_Float16)v.w};
        *(half4v*)(dst + i) = h;
    }
}

__global__ __launch_bounds__(256) void cvt_wo(const float* __restrict__ Wo,
                                              _Float16* __restrict__ Woh)
{
    const int n = DMODEL * DMODEL;
    for (int i = (blockIdx.x * 256 + threadIdx.x) * 4; i < n; i += gridDim.x * 256 * 4) {
        float4 v = *(const float4*)(Wo + i);
        half4v h = {(_Float16)v.x, (_Float16)v.y, (_Float16)v.z, (_Float16)v.w};
        *(half4v*)(Woh + i) = h;
    }
}

// ---------------------------------------------------------------------------
// V projection (m97 structure, fp16): 128x128 tile, BK=32, global_load_lds.
// fp16 tiles XOR-swizzled (4 chunks/row, chunk ^= row&3): pre-swizzled global
// source + swizzled fragment reads -> 2-way residual (free) vs 4-way before.
// Epilogue: +bv, transpose to v_hT [head][d][s] via wave-local LDS.
// ---------------------------------------------------------------------------
__global__ __launch_bounds__(256) void gemm_v(
    const _Float16* __restrict__ xh,    // [3328][1920]
    const _Float16* __restrict__ Wvh,   // [1920][1920]
    const float* __restrict__ bv,
    _Float16* __restrict__ v_hT)
{
    extern __shared__ __attribute__((aligned(16))) char smem[];
    _Float16* As = (_Float16*)smem;             // 128*32
    _Float16* Bs = (_Float16*)(smem + 8192);    // 128*32

    const int tid  = threadIdx.x;
    const int wave = tid >> 6;
    const int lane = tid & 63;
    const int l16  = lane & 15;
    const int quad = lane >> 4;

    const int m0 = blockIdx.x * 128;
    const int n0 = blockIdx.y * 128;
    const int wm = (wave >> 1) * 64;
    const int wn = (wave & 1) * 64;

    // source chunk pre-swizzled: chunk' = (lane&3) ^ (row&3), row = lane>>2
    const int schk = (((lane & 3) ^ ((lane >> 2) & 3)) << 3);   // halves
    const _Float16* gA = xh  + (size_t)(m0 + wave * 32 + (lane >> 2)) * DMODEL + schk;
    const _Float16* gB = Wvh + (size_t)(n0 + wave * 32 + (lane >> 2)) * DMODEL + schk;
    _Float16* lA = As + wave * 32 * 32;
    _Float16* lB = Bs + wave * 32 * 32;

    // fragment-read swizzle: physical chunk = quad ^ (row&3), row&3 = l16&3
    const int cf = ((quad ^ (l16 & 3)) << 3);   // halves

    f32x4 acc[4][4];
    #pragma unroll
    for (int j = 0; j < 4; ++j)
        #pragma unroll
        for (int i = 0; i < 4; ++i) acc[j][i] = (f32x4){0.f, 0.f, 0.f, 0.f};

    for (int k0 = 0; k0 < DMODEL; k0 += 32) {
        __syncthreads();
        gload16(lA,        gA + k0);
        gload16(lA + 512,  gA + 16 * DMODEL + k0);
        gload16(lB,        gB + k0);
        gload16(lB + 512,  gB + 16 * DMODEL + k0);
        __syncthreads();
        half8 af[4], bf[4];
        #pragma unroll
        for (int j = 0; j < 4; ++j)
            af[j] = *(const half8*)(As + (wm + j * 16 + l16) * 32 + cf);
        #pragma unroll
        for (int i = 0; i < 4; ++i)
            bf[i] = *(const half8*)(Bs + (wn + i * 16 + l16) * 32 + cf);
        #pragma unroll
        for (int j = 0; j < 4; ++j)
            #pragma unroll
            for (int i = 0; i < 4; ++i)
                acc[j][i] = mfma16h(af[j], bf[i], acc[j][i]);
    }
    __syncthreads();   // staging LDS dead; vt reuses it

    const int h = (n0 + wn) / 64;
    _Float16* vt = (_Float16*)smem + wave * 64 * 72;   // [64 d][72 pad]
    #pragma unroll
    for (int j = 0; j < 4; ++j)
        #pragma unroll
        for (int r = 0; r < 4; ++r)
            #pragma unroll
            for (int i = 0; i < 4; ++i)
                vt[(i * 16 + l16) * 72 + j * 16 + quad * 4 + r] =
                    (_Float16)(acc[j][i][r] + bv[n0 + wn + i * 16 + l16]);
    __asm__ volatile("" ::: "memory");   // order LDS writes before reads (same wave)
    const int dl = lane >> 3;
    const int sl = (lane & 7) << 3;
    #pragma unroll
    for (int t = 0; t < 8; ++t) {
        const int d = t * 8 + dl;
        half8 vv = *(const half8*)(vt + d * 72 + sl);
        *(half8*)(v_hT + (size_t)(h * HD + d) * S_TOT + m0 + wm + sl) = vv;
    }
}

// ---------------------------------------------------------------------------
// Q/K projection in split precision (bf16x2, 3 MFMAs) -> ~fp32-exact.
// fp32 tiles XOR-swizzled (8 chunks/row, chunk ^= row&7) -> conflict-free
// fragment reads (was 8-way). Epilogue: LN(+rope, q*0.125), dual store
// fp16 hi + fp16 lo*2^10.
// ---------------------------------------------------------------------------
__global__ __launch_bounds__(256) void gemm_qk(
    const float* __restrict__ hid, const float* __restrict__ enc,
    const float* __restrict__ Wq, const float* __restrict__ Wk,
    const float* __restrict__ bq, const float* __restrict__ bk,
    const float* __restrict__ rcos, const float* __restrict__ rsin,
    _Float16* __restrict__ q_h, _Float16* __restrict__ k_h,
    _Float16* __restrict__ q_lo, _Float16* __restrict__ k_lo)
{
    extern __shared__ __attribute__((aligned(16))) char smem[];
    float* As = (float*)smem;             // [128][32] f32
    float* Bs = (float*)(smem + 16384);   // [128][32] f32

    const int tid  = threadIdx.x;
    const int wave = tid >> 6;
    const int lane = tid & 63;
    const int l16  = lane & 15;
    const int quad = lane >> 4;

    const int m0  = blockIdx.x * 128;
    const int n0g = blockIdx.y * 128;
    const int zz  = (n0g >= DMODEL);       // 0=q 1=k (block-uniform; 128|1920)
    const int nloc = n0g - zz * DMODEL;
    const int wm = (wave >> 1) * 64;
    const int wn = (wave & 1) * 64;

    const float* aSrc = (m0 < S_TXT) ? (enc + (size_t)m0 * DMODEL)
                                     : (hid + (size_t)(m0 - S_TXT) * DMODEL);
    const float* bSrc = (zz ? Wk : Wq) + (size_t)nloc * DMODEL;

    // source chunk pre-swizzled: chunk' = (lane&7) ^ (row&7), row = lane>>3
    const int schk = (((lane & 7) ^ (lane >> 3)) << 2);   // f32 elems
    const float* gA = aSrc + (size_t)(wave * 32 + (lane >> 3)) * DMODEL + schk;
    const float* gB = bSrc + (size_t)(wave * 32 + (lane >> 3)) * DMODEL + schk;
    float* lA = As + wave * 32 * 32;
    float* lB = Bs + wave * 32 * 32;

    // fragment-read swizzle: logical chunks 2q, 2q+1 live at physical ^ (l16&7)
    const int s7 = l16 & 7;
    const int ca = ((2 * quad) ^ s7) << 2;        // f32 elems
    const int cb = ((2 * quad + 1) ^ s7) << 2;

    f32x4 acc[4][4];
    #pragma unroll
    for (int j = 0; j < 4; ++j)
        #pragma unroll
        for (int i = 0; i < 4; ++i) acc[j][i] = (f32x4){0.f, 0.f, 0.f, 0.f};

    for (int k0 = 0; k0 < DMODEL; k0 += 32) {
        __syncthreads();
        #pragma unroll
        for (int t = 0; t < 4; ++t) {
            gload16(lA + t * 256, gA + (size_t)(t * 8) * DMODEL + k0);
            gload16(lB + t * 256, gB + (size_t)(t * 8) * DMODEL + k0);
        }
        __syncthreads();
        bh8 ah[4], al[4], bhv[4], blv[4];
        #pragma unroll
        for (int j = 0; j < 4; ++j) {
            const int rb = (wm + j * 16 + l16) * 32;
            split8(As + rb + ca, As + rb + cb, ah[j], al[j]);
        }
        #pragma unroll
        for (int i = 0; i < 4; ++i) {
            const int rb = (wn + i * 16 + l16) * 32;
            split8(Bs + rb + ca, Bs + rb + cb, bhv[i], blv[i]);
        }
        #pragma unroll
        for (int j = 0; j < 4; ++j)
            #pragma unroll
            for (int i = 0; i < 4; ++i) {
                acc[j][i] = mfma16b(ah[j], bhv[i], acc[j][i]);
                acc[j][i] = mfma16b(al[j], bhv[i], acc[j][i]);
                acc[j][i] = mfma16b(ah[j], blv[i], acc[j][i]);
            }
    }

    const int h = (nloc + wn) / 64;        // head for this wave's 64 cols
    const float* bias = zz ? bk : bq;
    _Float16* dhi = zz ? k_h : q_h;
    _Float16* dlo = zz ? k_lo : q_lo;
    const float qscale = zz ? 1.f : 0.125f;   // fold 1/sqrt(64) into q
    const bool rope = (m0 >= S_TXT);          // block-uniform (128|256)

    #pragma unroll
    for (int j = 0; j < 4; ++j) {
        #pragma unroll
        for (int r = 0; r < 4; ++r) {
            const int s = m0 + wm + j * 16 + quad * 4 + r;
            float x[4], s1 = 0.f, s2 = 0.f;
            #pragma unroll
            for (int i = 0; i < 4; ++i) {
                x[i] = acc[j][i][r] + bias[nloc + wn + i * 16 + l16];
                s1 += x[i];
                s2 += x[i] * x[i];
            }
            #pragma unroll
            for (int off = 1; off <= 8; off <<= 1) {
                s1 += __shfl_xor(s1, off);
                s2 += __shfl_xor(s2, off);
            }
            const float mu   = s1 * (1.f / 64.f);
            const float var  = fmaxf(s2 * (1.f / 64.f) - mu * mu, 0.f);
            const float rstd = rsqrtf(var + 1e-5f);
            float xn[4];
            #pragma unroll
            for (int i = 0; i < 4; ++i) xn[i] = (x[i] - mu) * rstd;
            float o[4];
            if (rope) {
                const int pos = s - S_TXT;
                #pragma unroll
                for (int i = 0; i < 4; ++i) {
                    const int d = i * 16 + l16;
                    const float c  = rcos[(size_t)pos * HD + d];
                    const float si = rsin[(size_t)pos * HD + d];
                    const float rot = (i < 2) ? -xn[i ^ 2] : xn[i ^ 2];
                    o[i] = xn[i] * c + rot * si;
                }
            } else {
                #pragma unroll
                for (int i = 0; i < 4; ++i) o[i] = xn[i];
            }
            #pragma unroll
            for (int i = 0; i < 4; ++i) {
                const float vv = o[i] * qscale;
                const _Float16 hv = (_Float16)vv;
                const size_t idx = (size_t)(h * S_TOT + s) * HD + i * 16 + l16;
                dhi[idx] = hv;
                // residual scaled 2^10 to avoid fp16 denormals; attn folds 2^-10
                dlo[idx] = (_Float16)((vv - (float)hv) * 1024.f);
            }
        }
    }
}

// ---------------------------------------------------------------------------
// Flash attention, online softmax. s = qh*kh + 2^-10*(ql*kh + qh*kl).
// 32 q-rows per wave (block = 128 rows); K/Kl/V/Pl XOR-swizzled; conflicts = 0.
// Pipeline (R6-proven sync): K hi AND lo double-buffered, staged 1 tile ahead
// (overwrites always hit the opposite parity -> no WAR window, no fence needed
// — the R9 failure was a single-buffered Ksl whose overwrite-load could hoist
// above the raw s_barrier, which is not a compiler fence). V single-buffered,
// staged after b3 with lgkmcnt(0)+memory-clobber guard (drains this wave's V
// ds_reads AND fences compiler LDS-op motion across the raw barrier).
// vmcnt per wave (issue order K(t),V(t),K(t+1)): top=6 (drain K(t), leave
// V(t)+K(t+1)), mid=4 (drain V(t)); tail tile: 2/0.
// LDS: Khi[2][64][64] | Ksl[2][64][64] | Vs[64][64] | Pl[4][16][64] = 49152 B.
// ---------------------------------------------------------------------------
__global__ __launch_bounds__(256, 3) void attn(
    const _Float16* __restrict__ q_h,  const _Float16* __restrict__ q_lo,
    const _Float16* __restrict__ k_h,  const _Float16* __restrict__ k_lo,
    const _Float16* __restrict__ v_hT,
    _Float16* __restrict__ aout)
{
    extern __shared__ __attribute__((aligned(16))) char smem[];
    _Float16* KsB  = (_Float16*)smem;              // [2][64 kv][64 d] hi (swizzled)
    _Float16* KslB = (_Float16*)(smem + 16384);    // [2][64 kv][64 d] lo (swizzled)
    _Float16* Vs   = (_Float16*)(smem + 32768);    // [64 d][64 kv] (swizzled)
    _Float16* Pl   = (_Float16*)(smem + 40960);    // [4][16][64] (swizzled)

    const int tid  = threadIdx.x;
    const int wave = tid >> 6;
    const int lane = tid & 63;
    const int l16  = lane & 15;
    const int quad = lane >> 4;
    const int h  = blockIdx.y;
    const int q0 = blockIdx.x * 128 + wave * 32;

    // q fragments for 32 rows (j=0: rows 0..15, j=1: rows 16..31)
    const _Float16* qbase  = q_h  + (size_t)(h * S_TOT + q0) * HD;
    const _Float16* qlbase = q_lo + (size_t)(h * S_TOT + q0) * HD;
    half8 aq0[2], aq1[2], aql0[2], aql1[2];
    #pragma unroll
    for (int j = 0; j < 2; ++j) {
        aq0[j]  = *(const half8*)(qbase  + (j * 16 + l16) * HD + quad * 8);
        aq1[j]  = *(const half8*)(qbase  + (j * 16 + l16) * HD + 32 + quad * 8);
        aql0[j] = *(const half8*)(qlbase + (j * 16 + l16) * HD + quad * 8);
        aql1[j] = *(const half8*)(qlbase + (j * 16 + l16) * HD + 32 + quad * 8);
    }

    const _Float16* kbase  = k_h  + (size_t)h * S_TOT * HD;
    const _Float16* klbase = k_lo + (size_t)h * S_TOT * HD;
    const _Float16* vbase  = v_hT + (size_t)h * HD * S_TOT;

    // staging: per wave 16 rows each of K, Kl, V (2 gloads each).
    // Global source chunk pre-swizzled: chunk' = (lane&7) ^ (row&7); LDS dest
    // stays linear (global_load_lds constraint), reads XOR with row&7.
    const int srow = lane >> 3;                    // row within 8-row group
    const int schk = ((lane & 7) ^ srow) << 3;     // swizzled chunk, in halves
    const _Float16* gK  = kbase  + (size_t)(wave * 16 + srow) * HD + schk;
    const _Float16* gKl = klbase + (size_t)(wave * 16 + srow) * HD + schk;
    const _Float16* gV  = vbase  + (size_t)(wave * 16 + srow) * S_TOT + schk;

    // read-side swizzle: chunk quad lives at physical (quad ^ (row&7));
    // row&7 == l16&7 for rows i*16+l16 -> per-thread constant offsets.
    const int c0 = (quad ^ (l16 & 7)) << 3;        // halves
    const int c1 = c0 ^ 32;                        // chunk ^ 4

    f32x4 o[2][4];
    float m_i[2][4], l_i[2][4];
    #pragma unroll
    for (int j = 0; j < 2; ++j)
        #pragma unroll
        for (int i = 0; i < 4; ++i) {
            o[j][i] = (f32x4){0.f, 0.f, 0.f, 0.f};
            m_i[j][i] = -1e30f; l_i[j][i] = 0.f;
        }

    constexpr int NT = S_TOT / 64;   // 52

    // stage K hi+lo of tile (kv0/64) into parity p: 4 gloads/wave
    auto stageK = [&](int kv0, int p) {
        _Float16* lK  = KsB  + p * 4096 + wave * 1024;
        _Float16* lKl = KslB + p * 4096 + wave * 1024;
        gload16(lK,        gK  + (size_t)kv0 * HD);
        gload16(lK + 512,  gK  + (size_t)(kv0 + 8) * HD);
        gload16(lKl,       gKl + (size_t)kv0 * HD);
        gload16(lKl + 512, gKl + (size_t)(kv0 + 8) * HD);
    };
    // stage V into the single V buffer: 2 gloads/wave
    auto stageV = [&](int kv0) {
        _Float16* lV = Vs + wave * 1024;
        gload16(lV,       gV + kv0);
        gload16(lV + 512, gV + kv0 + 8 * S_TOT);
    };

    stageK(0, 0);                                  // prologue
    stageV(0);
    for (int t = 0; t < NT; ++t) {
        const int cur = t & 1;
        const bool isLast = (t == NT - 1);
        if (!isLast) {
            stageK((t + 1) * 64, cur ^ 1);         // issue next tile's K hi+lo
            // outstanding: [K(t)4, V(t)2, K(t+1)4] -> drain K(t)
            asm volatile("s_waitcnt vmcnt(6)" ::: "memory");
        } else {
            asm volatile("s_waitcnt vmcnt(2)" ::: "memory");   // leave V(t)
        }
        __builtin_amdgcn_s_barrier();              // b1: K hi+lo of t visible
        const _Float16* Ks  = KsB  + cur * 4096;
        const _Float16* Ksl = KslB + cur * 4096;

        // ---- scores (q pre-scaled by 1/8; lo terms folded with 2^-10) ----
        f32x4 sc[2][4];
        #pragma unroll
        for (int i = 0; i < 4; ++i) {
            const int rb = (i * 16 + l16) * 64;
            half8 b0 = *(const half8*)(Ks  + rb + c0);
            half8 b1 = *(const half8*)(Ks  + rb + c1);
            half8 d0 = *(const half8*)(Ksl + rb + c0);
            half8 d1 = *(const half8*)(Ksl + rb + c1);
            #pragma unroll
            for (int j = 0; j < 2; ++j) {
                f32x4 s  = (f32x4){0.f, 0.f, 0.f, 0.f};
                f32x4 s2 = (f32x4){0.f, 0.f, 0.f, 0.f};
                s  = mfma16h(aq0[j],  b0, s);   s  = mfma16h(aq1[j],  b1, s);
                s2 = mfma16h(aql0[j], b0, s2);  s2 = mfma16h(aql1[j], b1, s2);
                s2 = mfma16h(aq0[j],  d0, s2);  s2 = mfma16h(aq1[j],  d1, s2);
                sc[j][i] = s + s2 * 0.0009765625f;
            }
        }
        // ---- online softmax per j-half; Pl slab (swizzled rows of 64) ----
        half8 ap0[2], ap1[2];
        #pragma unroll
        for (int j = 0; j < 2; ++j) {
            #pragma unroll
            for (int r = 0; r < 4; ++r) {
                float mx = fmaxf(fmaxf(sc[j][0][r], sc[j][1][r]),
                                 fmaxf(sc[j][2][r], sc[j][3][r]));
                MAXDPP(mx, 0xB1);    // quad_perm xor1
                MAXDPP(mx, 0x4E);    // quad_perm xor2
                MAXDPP(mx, 0x124);   // row_ror:4
                MAXDPP(mx, 0x128);   // row_ror:8  -> max over 16-lane group
                const float mnew  = fmaxf(m_i[j][r], mx);
                const float alpha = __expf(m_i[j][r] - mnew);
                m_i[j][r] = mnew;
                const int ro  = quad * 4 + r;
                const int rsw = ((quad & 1) * 4 + r) << 3;   // (ro&7)<<3
                float rs = 0.f;
                #pragma unroll
                for (int i = 0; i < 4; ++i) {
                    float p = __expf(sc[j][i][r] - mnew);
                    rs += p;
                    Pl[wave * 1024 + ro * 64 + ((i * 16 + l16) ^ rsw)] = (_Float16)p;
                }
                l_i[j][r] = l_i[j][r] * alpha + rs;   // per-lane partial
                #pragma unroll
                for (int i = 0; i < 4; ++i) o[j][i][r] *= alpha;
            }
            __asm__ volatile("" ::: "memory");   // order P writes before reads
            // reads: row l16, chunks (quad^(l16&7)) and ^4 -> same c0/c1 geometry
            ap0[j] = *(const half8*)(Pl + wave * 1024 + l16 * 64 + c0);
            ap1[j] = *(const half8*)(Pl + wave * 1024 + l16 * 64 + c1);
            __asm__ volatile("" ::: "memory");   // reads before j=1 overwrites
        }
        // V(t) arrival: outstanding = [V(t)2, K(t+1)4] -> drain V(t)
        if (!isLast) asm volatile("s_waitcnt vmcnt(4)" ::: "memory");
        else         asm volatile("s_waitcnt vmcnt(0)" ::: "memory");
        __builtin_amdgcn_s_barrier();              // b2: all V(t) visible
        // ---- PV ----
        #pragma unroll
        for (int i = 0; i < 4; ++i) {
            const int rb = (i * 16 + l16) * 64;
            half8 vb0 = *(const half8*)(Vs + rb + c0);
            half8 vb1 = *(const half8*)(Vs + rb + c1);
            #pragma unroll
            for (int j = 0; j < 2; ++j) {
                o[j][i] = mfma16h(ap0[j], vb0, o[j][i]);
                o[j][i] = mfma16h(ap1[j], vb1, o[j][i]);
            }
        }
        if (!isLast) {
            // drain this wave's DS reads (V) before signaling b3; the clobber
            // also fences compiler LDS-op motion across the raw barrier.
            asm volatile("s_waitcnt lgkmcnt(0)" ::: "memory");
            __builtin_amdgcn_s_barrier();          // b3: V buffer free
            stageV((t + 1) * 64);                  // hides under next QK+sm
        }
    }
    // ---- final: reduce deferred l partials, normalize, store ----
    #pragma unroll
    for (int j = 0; j < 2; ++j)
        #pragma unroll
        for (int r = 0; r < 4; ++r) {
            float l = l_i[j][r];
            l += __shfl_xor(l, 1);
            l += __shfl_xor(l, 2);
            l += __shfl_xor(l, 4);
            l += __shfl_xor(l, 8);
            const float inv = 1.f / l;
            const int srow2 = q0 + j * 16 + quad * 4 + r;
            #pragma unroll
            for (int i = 0; i < 4; ++i)
                aout[(size_t)srow2 * DMODEL + h * HD + i * 16 + l16] =
                    (_Float16)(o[j][i][r] * inv);
        }
}

// ---------------------------------------------------------------------------
// Out projection (m97 structure) + bias + row remap, fp32 out.
// fp16 tiles XOR-swizzled (chunk ^= row&3), same as gemm_v.
// ---------------------------------------------------------------------------
__global__ __launch_bounds__(256) void gemm_out(
    const _Float16* __restrict__ A,    // [3328][1920] f16
    const _Float16* __restrict__ Woh,  // [1920][1920] f16
    const float* __restrict__ bo,
    float* __restrict__ out)
{
    extern __shared__ __attribute__((aligned(16))) char smem[];
    _Float16* As = (_Float16*)smem;
    _Float16* Bs = (_Float16*)(smem + 8192);

    const int tid  = threadIdx.x;
    const int wave = tid >> 6;
    const int lane = tid & 63;
    const int l16  = lane & 15;
    const int quad = lane >> 4;

    const int m0 = blockIdx.x * 128;
    const int n0 = blockIdx.y * 128;
    const int wm = (wave >> 1) * 64;
    const int wn = (wave & 1) * 64;

    const int schk = (((lane & 3) ^ ((lane >> 2) & 3)) << 3);   // halves
    const _Float16* gA = A   + (size_t)(m0 + wave * 32 + (lane >> 2)) * DMODEL + schk;
    const _Float16* gB = Woh + (size_t)(n0 + wave * 32 + (lane >> 2)) * DMODEL + schk;
    _Float16* lA = As + wave * 32 * 32;
    _Float16* lB = Bs + wave * 32 * 32;

    const int cf = ((quad ^ (l16 & 3)) << 3);   // halves

    f32x4 acc[4][4];
    #pragma unroll
    for (int j = 0; j < 4; ++j)
        #pragma unroll
        for (int i = 0; i < 4; ++i) acc[j][i] = (f32x4){0.f, 0.f, 0.f, 0.f};

    for (int k0 = 0; k0 < DMODEL; k0 += 32) {
        __syncthreads();
        gload16(lA,        gA + k0);
        gload16(lA + 512,  gA + 16 * DMODEL + k0);
        gload16(lB,        gB + k0);
        gload16(lB + 512,  gB + 16 * DMODEL + k0);
        __syncthreads();
        half8 af[4], bf[4];
        #pragma unroll
        for (int j = 0; j < 4; ++j)
            af[j] = *(const half8*)(As + (wm + j * 16 + l16) * 32 + cf);
        #pragma unroll
        for (int i = 0; i < 4; ++i)
            bf[i] = *(const half8*)(Bs + (wn + i * 16 + l16) * 32 + cf);
        #pragma unroll
        for (int j = 0; j < 4; ++j)
            #pragma unroll
            for (int i = 0; i < 4; ++i)
                acc[j][i] = mfma16h(af[j], bf[i], acc[j][i]);
    }
    #pragma unroll
    for (int j = 0; j < 4; ++j) {
        #pragma unroll
        for (int i = 0; i < 4; ++i) {
            const int n = n0 + wn + i * 16 + l16;
            const float bb = bo[n];
            #pragma unroll
            for (int r = 0; r < 4; ++r) {
                const int m = m0 + wm + j * 16 + quad * 4 + r;
                const int orow = (m >= S_TXT) ? (m - S_TXT) : (m + 3072);
                out[(size_t)orow * DMODEL + n] = acc[j][i][r] + bb;
            }
        }
    }
}

// ---------------------------------------------------------------------------
extern "C" void kernel_launch(void* const* d_in, const int* in_sizes, int n_in,
                              void* d_out, int out_size, void* d_ws, size_t ws_size,
                              hipStream_t stream) {
    const float* hid  = (const float*)d_in[0];
    const float* enc  = (const float*)d_in[1];
    const float* rcos = (const float*)d_in[2];
    const float* rsin = (const float*)d_in[3];
    const float* Wq   = (const float*)d_in[4];
    const float* bq   = (const float*)d_in[5];
    const float* Wk   = (const float*)d_in[6];
    const float* bk   = (const float*)d_in[7];
    const float* Wv   = (const float*)d_in[8];
    const float* bv   = (const float*)d_in[9];
    const float* Wo   = (const float*)d_in[10];
    const float* bo   = (const float*)d_in[11];

    // ws layout (51.1 MB, unchanged):
    //   A [0, 12.78M)        xh, later aout
    //   B [12.78M, 25.56M)   q_h, later Woh
    //   C [25.56M, 38.34M)   k_h
    //   D [38.34M, 51.12M)   v_hT
    // d_out (25.56 MB fp32) time-shared:
    //   phase 1 (cvt_xwv..gemm_v):   Wvh fp16 at [0, 7.37M)
    //   phase 2 (gemm_qk..attn):     q_lo at [0,12.78M), k_lo at [12.78M,25.56M)
    //   phase 3 (gemm_out):          final fp32 output
    char* ws = (char*)d_ws;
    _Float16* xh   = (_Float16*)(ws + 0);
    _Float16* aout = (_Float16*)(ws + 0);
    _Float16* q_h  = (_Float16*)(ws + 12779520);
    _Float16* Woh  = (_Float16*)(ws + 12779520);
    _Float16* k_h  = (_Float16*)(ws + 25559040);
    _Float16* v_hT = (_Float16*)(ws + 38338560);
    _Float16* Wvh  = (_Float16*)d_out;
    _Float16* q_lo = (_Float16*)d_out;
    _Float16* k_lo = (_Float16*)((char*)d_out + 12779520);

    cvt_xwv<<<dim3(128, 3), 256, 0, stream>>>(hid, enc, Wv, xh, Wvh);
    gemm_v<<<dim3(26, 15), 256, 36864, stream>>>(xh, Wvh, bv, v_hT);
    gemm_qk<<<dim3(26, 30), 256, 32768, stream>>>(
        hid, enc, Wq, Wk, bq, bk, rcos, rsin, q_h, k_h, q_lo, k_lo);
    attn<<<dim3(26, NHEAD), 256, 49152, stream>>>(q_h, q_lo, k_h, k_lo, v_hT, aout);
    cvt_wo<<<dim3(128), 256, 0, stream>>>(Wo, Woh);
    gemm_out<<<dim3(26, 15), 256, 16384, stream>>>(aout, Woh, bo, (float*)d_out);
}